// Round 3
// baseline (238.371 us; speedup 1.0000x reference)
//
#include <hip/hip_runtime.h>

// XMaskSwitchTop2Hard: per-4-group top-2 hard gate mixed with sigmoid(gate_logits).
// Forward math: gate_raw = gate_hard - sg(gate_soft) + gate_soft == gate_hard
// (up to ~1 ulp of gate_soft <= 2.4e-7, far below the 0.108 absmax threshold),
// so softmax is skipped. out[j] = keep_j ? x_j : r[g]*x_j, with top_k's
// lowest-index-wins tie-break replicated via stable ranking.
//
// R3: same as R2 but with native ext_vector_type(4) float so
// __builtin_nontemporal_store compiles (HIP_vector_type is rejected).

#define GROUPS_PER_ROW 1024  // 4096 hidden / GROUP=4

typedef float f4 __attribute__((ext_vector_type(4)));

__device__ __forceinline__ f4 gate_group(f4 v, float r) {
    float s0 = fabsf(v.x), s1 = fabsf(v.y), s2 = fabsf(v.z), s3 = fabsf(v.w);
    // rank_j = count of i beating j; i beats j iff s_i > s_j, or tie with i<j.
    int c0 = (s1 >  s0) + (s2 >  s0) + (s3 >  s0);
    int c1 = (s0 >= s1) + (s2 >  s1) + (s3 >  s1);
    int c2 = (s0 >= s2) + (s1 >= s2) + (s3 >  s2);
    int c3 = (s0 >= s3) + (s1 >= s3) + (s2 >= s3);
    f4 o;
    o.x = (c0 < 2) ? v.x : r * v.x;
    o.y = (c1 < 2) ? v.y : r * v.y;
    o.z = (c2 < 2) ? v.z : r * v.z;
    o.w = (c3 < 2) ? v.w : r * v.w;
    return o;
}

__global__ __launch_bounds__(256)
void xmask_top2_kernel(const f4* __restrict__ x4,
                       const float* __restrict__ gate_logits,
                       f4* __restrict__ out4,
                       int ngroups) {
    __shared__ float r_lds[GROUPS_PER_ROW];
    for (int i = threadIdx.x; i < GROUPS_PER_ROW; i += 256) {
        float gl = gate_logits[i];
        r_lds[i] = 1.0f / (1.0f + expf(-gl));
    }
    __syncthreads();

    const int stride = gridDim.x * blockDim.x;   // 524288: multiple of 1024
    int gi = blockIdx.x * blockDim.x + threadIdx.x;

    // Main loop: 4 independent loads in flight before compute/store.
    for (; gi + 3 * stride < ngroups; gi += 4 * stride) {
        f4 v0 = x4[gi];
        f4 v1 = x4[gi + stride];
        f4 v2 = x4[gi + 2 * stride];
        f4 v3 = x4[gi + 3 * stride];
        // stride % 1024 == 0 -> all four share the same gate group index.
        float r = r_lds[gi & (GROUPS_PER_ROW - 1)];

        f4 o0 = gate_group(v0, r);
        f4 o1 = gate_group(v1, r);
        f4 o2 = gate_group(v2, r);
        f4 o3 = gate_group(v3, r);

        __builtin_nontemporal_store(o0, &out4[gi]);
        __builtin_nontemporal_store(o1, &out4[gi + stride]);
        __builtin_nontemporal_store(o2, &out4[gi + 2 * stride]);
        __builtin_nontemporal_store(o3, &out4[gi + 3 * stride]);
    }
    // Tail (not taken for the fixed 33554432-group problem, kept for safety).
    for (; gi < ngroups; gi += stride) {
        float r = r_lds[gi & (GROUPS_PER_ROW - 1)];
        __builtin_nontemporal_store(gate_group(x4[gi], r), &out4[gi]);
    }
}

extern "C" void kernel_launch(void* const* d_in, const int* in_sizes, int n_in,
                              void* d_out, int out_size, void* d_ws, size_t ws_size,
                              hipStream_t stream) {
    const f4* x4 = (const f4*)d_in[0];
    const float* gate_logits = (const float*)d_in[1];
    f4* out4 = (f4*)d_out;

    int ngroups = out_size / 4;  // 134217728 / 4 = 33554432

    const int threads = 256;
    const int blocks = 2048;  // stride = 524288, multiple of GROUPS_PER_ROW
    xmask_top2_kernel<<<blocks, threads, 0, stream>>>(x4, gate_logits, out4, ngroups);
}

// Round 4
// 216.573 us; speedup vs baseline: 1.1007x; 1.1007x over previous
//
#include <hip/hip_runtime.h>

// XMaskSwitchTop2Hard: per-4-group top-2 hard gate mixed with sigmoid(gate_logits).
// Forward math: gate_raw = gate_hard - sg(gate_soft) + gate_soft == gate_hard
// (up to ~1 ulp of gate_soft <= 2.4e-7, far below the 0.108 absmax threshold),
// so softmax is skipped. out[j] = keep_j ? x_j : r[g]*x_j, with top_k's
// lowest-index-wins tie-break replicated via stable ranking.
//
// R4: revert R3's confounded pair (stride-4 unroll + NT stores regressed).
// Back to R1's simple grid-stride loop, with ONE structural change: r is
// loop-invariant (stride % 1024 == 0), so compute it once per thread from
// global (no LDS, no __syncthreads, no per-iteration lgkmcnt chain).
// x loads are nontemporal (read-once stream); stores stay normal.

#define GROUPS_PER_ROW 1024  // 4096 hidden / GROUP=4

typedef float f4 __attribute__((ext_vector_type(4)));

__device__ __forceinline__ f4 gate_group(f4 v, float r) {
    float s0 = fabsf(v.x), s1 = fabsf(v.y), s2 = fabsf(v.z), s3 = fabsf(v.w);
    // rank_j = count of i beating j; i beats j iff s_i > s_j, or tie with i<j.
    int c0 = (s1 >  s0) + (s2 >  s0) + (s3 >  s0);
    int c1 = (s0 >= s1) + (s2 >  s1) + (s3 >  s1);
    int c2 = (s0 >= s2) + (s1 >= s2) + (s3 >  s2);
    int c3 = (s0 >= s3) + (s1 >= s3) + (s2 >= s3);
    f4 o;
    o.x = (c0 < 2) ? v.x : r * v.x;
    o.y = (c1 < 2) ? v.y : r * v.y;
    o.z = (c2 < 2) ? v.z : r * v.z;
    o.w = (c3 < 2) ? v.w : r * v.w;
    return o;
}

__global__ __launch_bounds__(256)
void xmask_top2_kernel(const f4* __restrict__ x4,
                       const float* __restrict__ gate_logits,
                       f4* __restrict__ out4,
                       int ngroups) {
    const int stride = gridDim.x * blockDim.x;   // 524288: multiple of 1024
    int gi = blockIdx.x * blockDim.x + threadIdx.x;

    // stride % GROUPS_PER_ROW == 0 -> group index is loop-invariant per thread.
    float gl = gate_logits[gi & (GROUPS_PER_ROW - 1)];
    float r = 1.0f / (1.0f + expf(-gl));

    for (; gi < ngroups; gi += stride) {
        f4 v = __builtin_nontemporal_load(&x4[gi]);
        out4[gi] = gate_group(v, r);
    }
}

extern "C" void kernel_launch(void* const* d_in, const int* in_sizes, int n_in,
                              void* d_out, int out_size, void* d_ws, size_t ws_size,
                              hipStream_t stream) {
    const f4* x4 = (const f4*)d_in[0];
    const float* gate_logits = (const float*)d_in[1];
    f4* out4 = (f4*)d_out;

    int ngroups = out_size / 4;  // 134217728 / 4 = 33554432

    const int threads = 256;
    const int blocks = 2048;  // stride = 524288, multiple of GROUPS_PER_ROW
    xmask_top2_kernel<<<blocks, threads, 0, stream>>>(x4, gate_logits, out4, ngroups);
}

// Round 5
// 199.623 us; speedup vs baseline: 1.1941x; 1.0849x over previous
//
#include <hip/hip_runtime.h>

// XMaskSwitchTop2Hard: per-4-group top-2 hard gate mixed with sigmoid(gate_logits).
// Forward math: gate_raw = gate_hard - sg(gate_soft) + gate_soft == gate_hard
// (up to ~1 ulp of gate_soft <= 2.4e-7, far below the 0.108 absmax threshold),
// so softmax is skipped. out[j] = keep_j ? x_j : r[g]*x_j, with top_k's
// lowest-index-wins tie-break replicated via stable ranking.
//
// R5: block-contiguous 4x unroll for memory-level parallelism. Thread handles
// groups {base+tid, +256, +512, +768}: 4 independent loads in flight, block
// covers a contiguous 16 KB span per macro-iter (coalescing + DRAM locality
// preserved — unlike R3's 8MB-apart unroll). r values loop-invariant per
// thread (macro stride % 1024 == 0), computed once. Plain loads/stores.

#define GROUPS_PER_ROW 1024  // 4096 hidden / GROUP=4

typedef float f4 __attribute__((ext_vector_type(4)));

__device__ __forceinline__ f4 gate_group(f4 v, float r) {
    float s0 = fabsf(v.x), s1 = fabsf(v.y), s2 = fabsf(v.z), s3 = fabsf(v.w);
    // rank_j = count of i beating j; i beats j iff s_i > s_j, or tie with i<j.
    int c0 = (s1 >  s0) + (s2 >  s0) + (s3 >  s0);
    int c1 = (s0 >= s1) + (s2 >  s1) + (s3 >  s1);
    int c2 = (s0 >= s2) + (s1 >= s2) + (s3 >  s2);
    int c3 = (s0 >= s3) + (s1 >= s3) + (s2 >= s3);
    f4 o;
    o.x = (c0 < 2) ? v.x : r * v.x;
    o.y = (c1 < 2) ? v.y : r * v.y;
    o.z = (c2 < 2) ? v.z : r * v.z;
    o.w = (c3 < 2) ? v.w : r * v.w;
    return o;
}

__device__ __forceinline__ float sigmoidf_(float x) {
    return 1.0f / (1.0f + expf(-x));
}

__global__ __launch_bounds__(256)
void xmask_top2_kernel(const f4* __restrict__ x4,
                       const float* __restrict__ gate_logits,
                       f4* __restrict__ out4,
                       int ngroups) {
    const int tid = threadIdx.x;

    // Per-block span is 1024 groups/macro-iter; macro stride is a multiple of
    // 1024, so each subiteration's gate group index is loop-invariant.
    float r0 = sigmoidf_(gate_logits[tid]);
    float r1 = sigmoidf_(gate_logits[tid + 256]);
    float r2 = sigmoidf_(gate_logits[tid + 512]);
    float r3 = sigmoidf_(gate_logits[tid + 768]);

    const int macro = gridDim.x * 1024;          // 2097152 groups / macro-iter
    int g = blockIdx.x * 1024 + tid;

    for (; g + 768 < ngroups; g += macro) {
        f4 v0 = x4[g];
        f4 v1 = x4[g + 256];
        f4 v2 = x4[g + 512];
        f4 v3 = x4[g + 768];

        out4[g]       = gate_group(v0, r0);
        out4[g + 256] = gate_group(v1, r1);
        out4[g + 512] = gate_group(v2, r2);
        out4[g + 768] = gate_group(v3, r3);
    }
    // Tail (not taken for the fixed 33554432-group problem, kept for safety).
    for (; g < ngroups; g += 256) {
        float r = sigmoidf_(gate_logits[g & (GROUPS_PER_ROW - 1)]);
        out4[g] = gate_group(x4[g], r);
    }
}

extern "C" void kernel_launch(void* const* d_in, const int* in_sizes, int n_in,
                              void* d_out, int out_size, void* d_ws, size_t ws_size,
                              hipStream_t stream) {
    const f4* x4 = (const f4*)d_in[0];
    const float* gate_logits = (const float*)d_in[1];
    f4* out4 = (f4*)d_out;

    int ngroups = out_size / 4;  // 134217728 / 4 = 33554432

    const int threads = 256;
    const int blocks = 2048;  // macro stride = 2097152, 16 macro-iters exactly
    xmask_top2_kernel<<<blocks, threads, 0, stream>>>(x4, gate_logits, out4, ngroups);
}